// Round 4
// baseline (74.905 us; speedup 1.0000x reference)
//
#include <hip/hip_runtime.h>

// Problem constants (fixed by setup_inputs): N=65536 tokens, K=8, E=64 experts.
#define TOTAL   524288            // N*K flattened assignments
#define NEXP    64
#define TOPK    8
#define GSIZE   512               // blocks: 2 per CU -> 2 waves/SIMD latency hiding
#define BLOCK   256               // threads = 4 waves
#define NWAVE   4
#define CHUNK   (TOTAL / GSIZE)   // 1024 elements per block
#define WCHUNK  (CHUNK / NWAVE)   // 256 per wave
#define WROUNDS (WCHUNK / 64)     // 4 rounds of 64 lanes

// ---------------- Kernel A: per-block expert histogram (order-independent) --
__global__ __launch_bounds__(BLOCK) void hist_kernel(const int* __restrict__ idx,
                                                     int* __restrict__ counts) {
    __shared__ int hist[NWAVE][NEXP];
    const int tid = threadIdx.x, lane = tid & 63, wave = tid >> 6;
    hist[wave][lane] = 0;
    // Histogram order doesn't matter -> vectorized int4 load (1 load / wave chunk).
    const int4 v = ((const int4*)(idx + blockIdx.x * CHUNK + wave * WCHUNK))[lane];
    const int comp[4] = { v.x, v.y, v.z, v.w };
#pragma unroll
    for (int c = 0; c < 4; c++) {
        const int e = comp[c];
        unsigned long long m = ~0ULL;               // same-expert lane mask
#pragma unroll
        for (int bit = 0; bit < 6; bit++) {
            const unsigned long long bb = __ballot((e >> bit) & 1);
            m &= ((e >> bit) & 1) ? bb : ~bb;
        }
        const int leader = __ffsll((long long)m) - 1;
        if (lane == leader) hist[wave][e] += __popcll(m);  // distinct e per leader
    }
    __syncthreads();
    if (tid < NEXP)
        counts[blockIdx.x * NEXP + tid] =
            hist[0][tid] + hist[1][tid] + hist[2][tid] + hist[3][tid];
}

// ---------------- Kernel B: offsets + stable scatter (single barrier) -------
__global__ __launch_bounds__(BLOCK) void scatter_kernel(
        const float* __restrict__ scores,
        const int*   __restrict__ idx,
        const int*   __restrict__ counts,
        float*       __restrict__ out_scores,
        float*       __restrict__ out_tok,
        float*       __restrict__ out_cnt) {
    __shared__ int hist[NWAVE][NEXP];       // per-wave expert counts
    __shared__ int part_pre[NWAVE][NEXP];   // partial prefix (blocks < b)
    __shared__ int part_tot[NWAVE][NEXP];   // partial totals
    __shared__ int run[NWAVE][NEXP];        // running count within wave

    const int tid = threadIdx.x, lane = tid & 63, wave = tid >> 6, b = blockIdx.x;
    const unsigned long long ltmask = (1ULL << lane) - 1ULL;

    // --- counts scan: expert = lane, quarter of blocks = wave (coalesced rows) ---
    {
        int pre = 0, tot = 0;
        const int bb0 = wave * (GSIZE / NWAVE);
#pragma unroll 16
        for (int q = 0; q < GSIZE / NWAVE; q++) {
            const int bb = bb0 + q;
            const int c  = counts[bb * NEXP + lane];
            tot += c;
            pre += (bb < b) ? c : 0;
        }
        part_pre[wave][lane] = pre;
        part_tot[wave][lane] = tot;
    }

    // --- per-wave element loads + same-expert masks + wave histogram ---
    // Stability requires lane-major flat order within each round -> scalar loads.
    hist[wave][lane] = 0;
    run[wave][lane]  = 0;
    const int base = b * CHUNK + wave * WCHUNK;
    int                myE[WROUNDS];
    float              myS[WROUNDS];
    unsigned long long myM[WROUNDS];
#pragma unroll
    for (int r = 0; r < WROUNDS; r++) {
        const int i = base + r * 64 + lane;
        const int e = idx[i];
        myE[r] = e;
        myS[r] = scores[i];
        unsigned long long m = ~0ULL;
#pragma unroll
        for (int bit = 0; bit < 6; bit++) {
            const unsigned long long bb = __ballot((e >> bit) & 1);
            m &= ((e >> bit) & 1) ? bb : ~bb;
        }
        myM[r] = m;
        const int leader = __ffsll((long long)m) - 1;
        if (lane == leader) hist[wave][e] += __popcll(m);
    }
    __syncthreads();   // the ONLY block barrier

    // --- every wave redundantly: combine partials + shfl expert ex-scan ---
    int exoff_reg;     // per-lane register: start offset for expert==lane, this wave
    {
        const int p = part_pre[0][lane] + part_pre[1][lane] +
                      part_pre[2][lane] + part_pre[3][lane];
        const int t = part_tot[0][lane] + part_tot[1][lane] +
                      part_tot[2][lane] + part_tot[3][lane];
        if (b == 0 && wave == 0) out_cnt[lane] = (float)t;  // num_tokens_per_expert
        int inc = t;                                         // 64-lane inclusive scan
#pragma unroll
        for (int d = 1; d < 64; d <<= 1) {
            const int v = __shfl_up(inc, d, 64);
            if (lane >= d) inc += v;
        }
        int off = (inc - t) + p;                             // ex-scan + block prefix
        for (int w = 0; w < wave; w++) off += hist[w][lane]; // earlier waves' counts
        exoff_reg = off;
    }

    // --- stable scatter: wave-lockstep rounds, exoff via ds_bpermute ---
#pragma unroll
    for (int r = 0; r < WROUNDS; r++) {
        const int e = myE[r];
        const unsigned long long m = myM[r];
        const int inwave = __popcll(m & ltmask);
        const int rn     = run[wave][e];                       // pre-round running
        const int boff   = __builtin_amdgcn_ds_bpermute(e << 2, exoff_reg);
        const int pos    = boff + rn + inwave;
        out_scores[pos] = myS[r];
        out_tok[pos]    = (float)((base + r * 64 + lane) >> 3);  // /TOPK exact in fp32
        __builtin_amdgcn_wave_barrier();
        const int leader = __ffsll((long long)m) - 1;
        if (lane == leader) run[wave][e] = rn + __popcll(m);
        __builtin_amdgcn_wave_barrier();
    }
}

extern "C" void kernel_launch(void* const* d_in, const int* in_sizes, int n_in,
                              void* d_out, int out_size, void* d_ws, size_t ws_size,
                              hipStream_t stream) {
    const float* top_scores = (const float*)d_in[0];
    const int*   sel_idx    = (const int*)d_in[1];
    float*       out        = (float*)d_out;
    int*         counts     = (int*)d_ws;   // GSIZE*NEXP ints = 128 KB

    // d_out layout: [scores_sorted (TOTAL)] [token_idx_sorted (TOTAL)] [counts (NEXP)]
    float* out_scores = out;
    float* out_tok    = out + TOTAL;
    float* out_cnt    = out + 2 * TOTAL;

    hist_kernel<<<GSIZE, BLOCK, 0, stream>>>(sel_idx, counts);
    scatter_kernel<<<GSIZE, BLOCK, 0, stream>>>(top_scores, sel_idx, counts,
                                                out_scores, out_tok, out_cnt);
}